// Round 1
// baseline (374.051 us; speedup 1.0000x reference)
//
#include <hip/hip_runtime.h>

// SABlock: x(4,512,64,64) -> phi/theta/g (1x1 convs, CI=256) -> f=theta^T@phi
// -> softmax -> y=a@g^T -> w_mask 1x1 conv -> out(4,512,64,64)
// All GEMMs fp16-in / fp32-accumulate on MFMA 16x16x32_f16 (error budget:
// predicted absmax ~2e-3 vs threshold 1.23e-2).

#define BB 4
#define CC 512
#define NN_SP 4096   // H*W
#define CI 256

typedef _Float16 f16x8 __attribute__((ext_vector_type(8)));
typedef float f32x4 __attribute__((ext_vector_type(4)));

__device__ __forceinline__ void async16(const void* gsrc, void* ldst) {
  __builtin_amdgcn_global_load_lds(
      (const __attribute__((address_space(1))) unsigned int*)gsrc,
      (__attribute__((address_space(3))) unsigned int*)ldst, 16, 0, 0);
}

// ---------------- weight convert: fp32 -> f16, stack [w_phi; w_theta] ----------------
__global__ __launch_bounds__(256) void convert_w(
    const float* __restrict__ wphi, const float* __restrict__ wtheta,
    const float* __restrict__ wg, const float* __restrict__ wmask,
    _Float16* __restrict__ wpt, _Float16* __restrict__ wgh, _Float16* __restrict__ wmh) {
  int i = blockIdx.x * 256 + threadIdx.x;
  if (i < 512 * 512) {                       // wpt rows: 0..255 phi, 256..511 theta
    int row = i >> 9, k = i & 511;
    float v = (row < 256) ? wphi[row * 512 + k] : wtheta[(row - 256) * 512 + k];
    wpt[i] = (_Float16)v;
  } else if (i < 512 * 512 + 256 * 512) {
    int j = i - 512 * 512;
    wgh[j] = (_Float16)wg[j];
  } else {
    int j = i - 512 * 512 - 256 * 512;
    wmh[j] = (_Float16)wmask[j];
  }
}

// ---------------- x (B,512,4096) fp32 -> x_T (B,4096,512) f16 ----------------
__global__ __launch_bounds__(256) void transpose_x(const float* __restrict__ x,
                                                   _Float16* __restrict__ xT) {
  __shared__ float tile[64][65];   // +1 pad: conflict-free column read
  const int n0 = blockIdx.x * 64, c0 = blockIdx.y * 64, b = blockIdx.z;
  const int tx = threadIdx.x & 63, ty = threadIdx.x >> 6;
  const float* xb = x + (long long)b * CC * NN_SP;
#pragma unroll
  for (int i = 0; i < 16; ++i) {
    int row = i * 4 + ty;
    tile[row][tx] = xb[(long long)(c0 + row) * NN_SP + n0 + tx];
  }
  __syncthreads();
  _Float16* xTb = xT + (long long)b * NN_SP * CC;
#pragma unroll
  for (int i = 0; i < 16; ++i) {
    int row = i * 4 + ty;
    xTb[(long long)(n0 + row) * CC + c0 + tx] = (_Float16)tile[tx][row];
  }
}

// ---------------- generic gemm_bt: C[m,n] = sum_k A[m,k] * Bt[n,k] ----------------
// A (M,K) k-contig, Bt (N,K) k-contig, C row-major (M,N). 128x128 tile, BK=32.
// m97 structure: global_load_lds width-16 staging, 4 waves 2x2, 16 MFMA/wave/K-step.
template <int M, int NT, int K, bool F16OUT>
__global__ __launch_bounds__(256, 2) void gemm_bt(
    const _Float16* __restrict__ Ab, const _Float16* __restrict__ Btb,
    void* __restrict__ Cb, long long sA, long long sB, long long sC) {
  __shared__ _Float16 As[128 * 32];
  __shared__ _Float16 Bs[128 * 32];
  const int tid = threadIdx.x, lane = tid & 63, w = tid >> 6;
  const int wm = w >> 1, wn = w & 1;
  const int l15 = lane & 15, lq = lane >> 4;
  const int b = blockIdx.z;
  const _Float16* A = Ab + (long long)b * sA;
  const _Float16* Bt = Btb + (long long)b * sB;
  const int m0 = blockIdx.y * 128, n0 = blockIdx.x * 128;

  f32x4 acc[4][4];
#pragma unroll
  for (int i = 0; i < 4; ++i)
#pragma unroll
    for (int j = 0; j < 4; ++j) acc[i][j] = (f32x4){0.f, 0.f, 0.f, 0.f};

  for (int k0 = 0; k0 < K; k0 += 32) {
    __syncthreads();  // previous LDS reads done before overwrite
#pragma unroll
    for (int j = 0; j < 2; ++j) {
      int chw = j * 256 + w * 64;      // wave-uniform chunk base
      int ch = chw + lane;
      int row = ch >> 2, kc = ch & 3;  // 4 x 16B chunks per 32-k row segment
      async16(A + (long long)(m0 + row) * K + k0 + kc * 8, (void*)(As + chw * 8));
      async16(Bt + (long long)(n0 + row) * K + k0 + kc * 8, (void*)(Bs + chw * 8));
    }
    __syncthreads();  // vmcnt(0) drain + barrier
    f16x8 af[4], bf[4];
#pragma unroll
    for (int mt = 0; mt < 4; ++mt)
      af[mt] = *(const f16x8*)(As + (wm * 64 + mt * 16 + l15) * 32 + lq * 8);
#pragma unroll
    for (int nt = 0; nt < 4; ++nt)
      bf[nt] = *(const f16x8*)(Bs + (wn * 64 + nt * 16 + l15) * 32 + lq * 8);
#pragma unroll
    for (int mt = 0; mt < 4; ++mt)
#pragma unroll
      for (int nt = 0; nt < 4; ++nt)
        acc[mt][nt] = __builtin_amdgcn_mfma_f32_16x16x32_f16(af[mt], bf[nt], acc[mt][nt], 0, 0, 0);
  }

#pragma unroll
  for (int mt = 0; mt < 4; ++mt)
#pragma unroll
    for (int nt = 0; nt < 4; ++nt)
#pragma unroll
      for (int r = 0; r < 4; ++r) {
        int row = m0 + wm * 64 + mt * 16 + lq * 4 + r;  // C/D: row=(lane>>4)*4+reg
        int col = n0 + wn * 64 + nt * 16 + l15;         //      col=lane&15
        if (F16OUT)
          ((_Float16*)Cb + (long long)b * sC)[(long long)row * NT + col] = (_Float16)acc[mt][nt][r];
        else
          ((float*)Cb + (long long)b * sC)[(long long)row * NT + col] = acc[mt][nt][r];
      }
}

// ---------------- flash attention ----------------
// pt (B,4096,512): cols 0..255 = phi_T, 256..511 = theta_T (c-contiguous)
// g  (B,256,4096): m-contiguous.  yT (B,4096,256) f16 out.
// Block: 64 q-rows, 4 waves x 16 rows. kv tiles of 128, online softmax in regs.
__global__ __launch_bounds__(256, 2) void flash_attn(
    const _Float16* __restrict__ pt, const _Float16* __restrict__ g,
    _Float16* __restrict__ yT) {
  __shared__ _Float16 Qs[64 * 256];    // theta tile, resident (32 KB)
  __shared__ _Float16 Stg[128 * 64];   // phi chunk [128][64] / g chunk [256][32] (16 KB)
  __shared__ _Float16 Ps[64 * 128];    // P in A-operand layout (16 KB)
  const int tid = threadIdx.x, lane = tid & 63, w = tid >> 6;
  const int l15 = lane & 15, lq = lane >> 4;
  const int b = blockIdx.y;
  const int q0 = blockIdx.x * 64;
  const _Float16* ptb = pt + (long long)b * NN_SP * 512;
  const _Float16* gb = g + (long long)b * CI * NN_SP;

  // stage theta rows q0..q0+63 (cols 256..511 of pt) -> Qs[64][256]
#pragma unroll
  for (int j = 0; j < 8; ++j) {
    int chw = j * 256 + w * 64;
    int ch = chw + lane;
    int row = ch >> 5, cc = ch & 31;  // 32 chunks per 256-elem row
    async16(ptb + (long long)(q0 + row) * 512 + 256 + cc * 8, (void*)(Qs + chw * 8));
  }

  f32x4 yacc[16];
#pragma unroll
  for (int i = 0; i < 16; ++i) yacc[i] = (f32x4){0.f, 0.f, 0.f, 0.f};
  float mrow[4] = {-3e38f, -3e38f, -3e38f, -3e38f};
  float lrow[4] = {0.f, 0.f, 0.f, 0.f};

  for (int kv0 = 0; kv0 < NN_SP; kv0 += 128) {
    f32x4 S[8];
#pragma unroll
    for (int i = 0; i < 8; ++i) S[i] = (f32x4){0.f, 0.f, 0.f, 0.f};

    // ---- S = theta_tile @ phi_tile^T, K=256 in 4 chunks of 64 ----
    for (int kc = 0; kc < 4; ++kc) {
      __syncthreads();  // previous Stg consumers done
#pragma unroll
      for (int j = 0; j < 4; ++j) {
        int chw = j * 256 + w * 64;
        int ch = chw + lane;
        int row = ch >> 3, cc = ch & 7;  // phi chunk [128 kv][64 c]
        async16(ptb + (long long)(kv0 + row) * 512 + kc * 64 + cc * 8, (void*)(Stg + chw * 8));
      }
      __syncthreads();
#pragma unroll
      for (int k2 = 0; k2 < 2; ++k2) {
        f16x8 a = *(const f16x8*)(Qs + (w * 16 + l15) * 256 + kc * 64 + k2 * 32 + lq * 8);
#pragma unroll
        for (int nt = 0; nt < 8; ++nt) {
          f16x8 bf = *(const f16x8*)(Stg + (nt * 16 + l15) * 64 + k2 * 32 + lq * 8);
          S[nt] = __builtin_amdgcn_mfma_f32_16x16x32_f16(a, bf, S[nt], 0, 0, 0);
        }
      }
    }

    // ---- online softmax, all stats in registers (wave owns its 16 rows) ----
#pragma unroll
    for (int r = 0; r < 4; ++r) {
      float mx = S[0][r];
#pragma unroll
      for (int nt = 1; nt < 8; ++nt) mx = fmaxf(mx, S[nt][r]);
#pragma unroll
      for (int d = 1; d < 16; d <<= 1) mx = fmaxf(mx, __shfl_xor(mx, d, 64));
      float nm = fmaxf(mrow[r], mx);
      float alpha = __expf(mrow[r] - nm);
      mrow[r] = nm;
      float psum = 0.f;
#pragma unroll
      for (int nt = 0; nt < 8; ++nt) {
        float p = __expf(S[nt][r] - nm);
        S[nt][r] = p;
        psum += p;
      }
#pragma unroll
      for (int d = 1; d < 16; d <<= 1) psum += __shfl_xor(psum, d, 64);
      lrow[r] = lrow[r] * alpha + psum;
#pragma unroll
      for (int nt = 0; nt < 16; ++nt) yacc[nt][r] *= alpha;
    }

    // ---- P: C/D layout -> LDS A-operand layout (row-major, m contiguous) ----
#pragma unroll
    for (int r = 0; r < 4; ++r)
#pragma unroll
      for (int nt = 0; nt < 8; ++nt)
        Ps[(w * 16 + lq * 4 + r) * 128 + nt * 16 + l15] = (_Float16)S[nt][r];

    // ---- y += P @ g_tile^T, k(=m) in 4 chunks of 32 ----
    for (int km = 0; km < 4; ++km) {
      __syncthreads();  // phi reads / previous g reads done before overwrite
#pragma unroll
      for (int j = 0; j < 4; ++j) {
        int chw = j * 256 + w * 64;
        int ch = chw + lane;
        int row = ch >> 2, mm = ch & 3;  // g chunk [256 c][32 m]
        async16(gb + (long long)row * NN_SP + kv0 + km * 32 + mm * 8, (void*)(Stg + chw * 8));
      }
      __syncthreads();
      f16x8 a = *(const f16x8*)(Ps + (w * 16 + l15) * 128 + km * 32 + lq * 8);
#pragma unroll
      for (int nt = 0; nt < 16; ++nt) {
        f16x8 bf = *(const f16x8*)(Stg + (nt * 16 + l15) * 32 + lq * 8);
        yacc[nt] = __builtin_amdgcn_mfma_f32_16x16x32_f16(a, bf, yacc[nt], 0, 0, 0);
      }
    }
  }

  // ---- epilogue: y / l -> yT (B,4096,256) f16 ----
#pragma unroll
  for (int r = 0; r < 4; ++r) {
    float inv = 1.f / lrow[r];
    int row = q0 + w * 16 + lq * 4 + r;
#pragma unroll
    for (int nt = 0; nt < 16; ++nt)
      yT[(long long)b * NN_SP * CI + (long long)row * CI + nt * 16 + l15] =
          (_Float16)(yacc[nt][r] * inv);
  }
}

extern "C" void kernel_launch(void* const* d_in, const int* in_sizes, int n_in,
                              void* d_out, int out_size, void* d_ws, size_t ws_size,
                              hipStream_t stream) {
  const float* x = (const float*)d_in[0];
  const float* w_phi = (const float*)d_in[1];
  const float* w_theta = (const float*)d_in[2];
  const float* w_g = (const float*)d_in[3];
  const float* w_mask = (const float*)d_in[4];
  float* out = (float*)d_out;
  char* ws = (char*)d_ws;

  // workspace layout (51.4 MB total)
  _Float16* xT = (_Float16*)(ws);                 // (B,4096,512)  16.78 MB
  _Float16* pt = (_Float16*)(ws + 16777216);      // (B,4096,512)  16.78 MB  [phi|theta]
  _Float16* gB = (_Float16*)(ws + 33554432);      // (B,256,4096)   8.39 MB
  _Float16* yT = (_Float16*)(ws + 41943040);      // (B,4096,256)   8.39 MB
  _Float16* wpt = (_Float16*)(ws + 50331648);     // (512,512)
  _Float16* wg = (_Float16*)(ws + 50855936);      // (256,512)
  _Float16* wm = (_Float16*)(ws + 51118080);      // (512,256)

  convert_w<<<2048, 256, 0, stream>>>(w_phi, w_theta, w_g, w_mask, wpt, wg, wm);
  transpose_x<<<dim3(64, 8, 4), 256, 0, stream>>>(x, xT);
  // PT[n, {phi|theta}] = xT @ wpt^T : M=4096, N=512, K=512, per batch
  gemm_bt<4096, 512, 512, true><<<dim3(4, 32, 4), 256, 0, stream>>>(
      xT, wpt, pt, 4096LL * 512, 0, 4096LL * 512);
  // g[c, n] = wg @ x : M=256, N=4096, K=512 (Bt = xT), per batch
  gemm_bt<256, 4096, 512, true><<<dim3(32, 2, 4), 256, 0, stream>>>(
      wg, xT, gB, 0, 4096LL * 512, 256LL * 4096);
  // attention: 64-row q tiles
  flash_attn<<<dim3(64, 4), 256, 0, stream>>>(pt, gB, yT);
  // out[o, n] = wm @ y : M=512, N=4096, K=256 (Bt = yT), fp32 out, per batch
  gemm_bt<512, 4096, 256, false><<<dim3(32, 4, 4), 256, 0, stream>>>(
      wm, yT, out, 0, 4096LL * 256, 512LL * 4096);
}